// Round 4
// baseline (281337.329 us; speedup 1.0000x reference)
//
#include <hip/hip_runtime.h>

#define HH    100
#define G4    400
#define LSEQ  168
#define STEPS 48
#define NTICK 8066     // L0 at tick t (t<8064), L1 at tick t-1
#define NPOOL 176      // 176 row-units streamed from L2
#define SHP   112      // padded h stride (zeros beyond 100)

__device__ __forceinline__ float sigmoidf_(float x) {
    return 1.0f / (1.0f + __expf(-x));
}
__device__ __forceinline__ float tanhf_(float x) {
    return 1.0f - 2.0f / (__expf(2.0f * x) + 1.0f);
}

// Pool row-units u:
//   u <  16 : Whh0 row 384+u  (input h0)
//   u <  32 : Wih1 row 368+u  (input h0)   [u=16..31 -> rows 384..399]
//   u < 176 : Whh1 row 224+u  (input h1)   [u=32..175 -> rows 256..399]
// Packed for coalesced dwordx4: float index ((q*7+i)*NPOOL+u)*4+c <-> k=28q+4i+c
__global__ void prep_kernel(const float* __restrict__ Whh0,
                            const float* __restrict__ Wih1,
                            const float* __restrict__ Whh1,
                            float* __restrict__ wsT) {
    int idx = blockIdx.x * 256 + threadIdx.x;
    if (idx >= SHP * NPOOL) return;
    int k = idx / NPOOL, u = idx % NPOOL;
    float v = 0.0f;
    if (k < HH) {
        if (u < 16)       v = Whh0[(384 + u) * HH + k];
        else if (u < 32)  v = Wih1[(368 + u) * HH + k];
        else              v = Whh1[(224 + u) * HH + k];
    }
    int q = k / 28, r = k % 28, i = r / 4, c = r % 4;
    wsT[((q * 7 + i) * NPOOL + u) * 4 + c] = v;
}

// 512 threads = 8 waves = 2 waves/SIMD -> 256 combined V+A regs/thread.
// 200 weight floats per thread pinned into AGPRs (asm "+a" inside the loop).
// Unit map: t<384: w0=Whh0 row t, w1=Wih1 row t (input h0)
//           t>=384: w0=Whh1 row t-384, w1=Whh1 row t-256 (input h1)
__global__
__attribute__((amdgpu_flat_work_group_size(512, 512), amdgpu_waves_per_eu(2, 2)))
void lstm_kernel(const float* __restrict__ X,     // (512,168)
                 const float* __restrict__ Wih0,  // (400,1)
                 const float* __restrict__ Whh0,  // (400,100)
                 const float* __restrict__ bih0,
                 const float* __restrict__ bhh0,
                 const float* __restrict__ Wih1,  // (400,100)
                 const float* __restrict__ Whh1,  // (400,100)
                 const float* __restrict__ bih1,
                 const float* __restrict__ bhh1,
                 const float* __restrict__ fcw,   // (100)
                 const float* __restrict__ fcb,   // (1)
                 const float* __restrict__ wsT,   // pool, packed
                 float* __restrict__ out)         // (512,48)
{
    __shared__ __align__(16) float shs[4 * SHP];  // [0]=L0b0 [SHP]=L0b1 [2S]=L1b0 [3S]=L1b1
    __shared__ float g0s[2][G4];                  // Whh0 . h0 partials (rows 0..383)
    __shared__ float g1a[2][G4];                  // Wih1 . h0 partials (rows 0..383)
    __shared__ float g1b[2][256];                 // Whh1 . h1 partials (rows 0..255)
    __shared__ float pp[2][NPOOL][5];             // pool quarter partials (stride 5)
    __shared__ float sb0[G4], sb1[G4], sw0[G4], sfcw[HH];
    __shared__ float yacc[2], ybuf[2];

    const int t  = threadIdx.x;
    const int wg = blockIdx.x;
    const int b0 = wg * 2;

    // ---- one-time init ----
    if (t < 4 * SHP) shs[t] = 0.0f;
    if (t < G4) {
        sb0[t] = bih0[t] + bhh0[t];
        sb1[t] = bih1[t] + bhh1[t];
        sw0[t] = Wih0[t];
    }
    if (t < HH) sfcw[t] = fcw[t];
    if (t == 0) { yacc[0] = yacc[1] = 0.0f; ybuf[0] = ybuf[1] = 0.0f; }
    const float fcb0 = fcb[0];

    // ---- register-resident weights: 2 rows x 100 = 200 floats ----
    const float *p0, *p1;
    if (t < 384) { p0 = Whh0 + t * HH;         p1 = Wih1 + t * HH; }
    else         { p0 = Whh1 + (t - 384) * HH; p1 = Whh1 + (t - 256) * HH; }
    float w0[HH], w1[HH];
    #pragma unroll
    for (int j = 0; j < 25; ++j) {
        float4 a = ((const float4*)p0)[j];
        w0[4*j] = a.x; w0[4*j+1] = a.y; w0[4*j+2] = a.z; w0[4*j+3] = a.w;
        float4 b = ((const float4*)p1)[j];
        w1[4*j] = b.x; w1[4*j+1] = b.y; w1[4*j+2] = b.z; w1[4*j+3] = b.w;
    }

    // main-FMA h base offset (h0 for t<384, h1 for t>=384)
    const int hbase = (t < 384) ? 0 : 2 * SHP;

    // pool tasks: task1 = t, task2 = 512+t (t<192)
    const int u1 = t % NPOOL, q1 = t / NPOOL;
    const int u2 = (160 + t) % NPOOL, q2 = (512 + t) / NPOOL;
    const bool has2 = (t < 192);
    const float* wp1 = wsT + ((q1 * 7) * NPOOL + u1) * 4;
    const float* wp2 = wsT + ((q2 * 7) * NPOOL + u2) * 4;
    const int hb1 = (u1 < 32) ? 0 : 2 * SHP;  const int k01 = 28 * q1;
    const int hb2 = (u2 < 32) ? 0 : 2 * SHP;  const int k02 = 28 * q2;

    // cell-update params
    float c0 = 0.0f, c1 = 0.0f;
    const int ub = (t < 200) ? (t / 100) : ((t - 200) / 100);
    const int uj = (t < 200) ? (t % 100) : ((t - 200) % 100);
    const float* xrow = X + (b0 + ub) * LSEQ;

    __syncthreads();

    #pragma unroll 1
    for (int tick = 0; tick < NTICK; ++tick) {
        const bool ydtick = (tick >= 2) && ((tick - 2) % LSEQ == LSEQ - 1);

        // Pin all 200 weight floats into AGPRs at every iteration: the
        // allocator cannot demote them to scratch (R1/R2/R3 failure mode).
        #pragma unroll
        for (int j = 0; j < HH; j += 4) {
            asm volatile("" : "+a"(w0[j]), "+a"(w0[j+1]), "+a"(w0[j+2]), "+a"(w0[j+3]),
                             "+a"(w1[j]), "+a"(w1[j+1]), "+a"(w1[j+2]), "+a"(w1[j+3]));
        }

        // ================= Phase A: all FMA work =================
        {
            float a00 = 0.f, a01 = 0.f, a10 = 0.f, a11 = 0.f;
            #pragma unroll
            for (int kc = 0; kc < 25; ++kc) {
                const float4 hA = *(const float4*)(&shs[hbase + 4 * kc]);
                const float4 hB = *(const float4*)(&shs[hbase + SHP + 4 * kc]);
                a00 += w0[4*kc+0]*hA.x; a01 += w0[4*kc+0]*hB.x;
                a10 += w1[4*kc+0]*hA.x; a11 += w1[4*kc+0]*hB.x;
                a00 += w0[4*kc+1]*hA.y; a01 += w0[4*kc+1]*hB.y;
                a10 += w1[4*kc+1]*hA.y; a11 += w1[4*kc+1]*hB.y;
                a00 += w0[4*kc+2]*hA.z; a01 += w0[4*kc+2]*hB.z;
                a10 += w1[4*kc+2]*hA.z; a11 += w1[4*kc+2]*hB.z;
                a00 += w0[4*kc+3]*hA.w; a01 += w0[4*kc+3]*hB.w;
                a10 += w1[4*kc+3]*hA.w; a11 += w1[4*kc+3]*hB.w;
            }
            if (t < 384) {
                g0s[0][t] = a00; g0s[1][t] = a01;
                g1a[0][t] = a10; g1a[1][t] = a11;
            } else {
                const int r1 = t - 384, r2 = t - 256;
                g1b[0][r1] = a00; g1b[1][r1] = a01;
                g1b[0][r2] = a10; g1b[1][r2] = a11;
            }
        }
        // pool tasks (weights stream from L1/L2, dwordx4 coalesced)
        {
            float pa = 0.f, pb = 0.f;
            #pragma unroll
            for (int i = 0; i < 7; ++i) {
                const float4 w4 = *(const float4*)(wp1 + i * NPOOL * 4);
                const float4 hA = *(const float4*)(&shs[hb1 + k01 + 4 * i]);
                const float4 hB = *(const float4*)(&shs[hb1 + SHP + k01 + 4 * i]);
                pa += w4.x*hA.x + w4.y*hA.y + w4.z*hA.z + w4.w*hA.w;
                pb += w4.x*hB.x + w4.y*hB.y + w4.z*hB.z + w4.w*hB.w;
            }
            pp[0][u1][q1] = pa; pp[1][u1][q1] = pb;
            if (has2) {
                float qa = 0.f, qb = 0.f;
                #pragma unroll
                for (int i = 0; i < 7; ++i) {
                    const float4 w4 = *(const float4*)(wp2 + i * NPOOL * 4);
                    const float4 hA = *(const float4*)(&shs[hb2 + k02 + 4 * i]);
                    const float4 hB = *(const float4*)(&shs[hb2 + SHP + k02 + 4 * i]);
                    qa += w4.x*hA.x + w4.y*hA.y + w4.z*hA.z + w4.w*hA.w;
                    qb += w4.x*hB.x + w4.y*hB.y + w4.z*hB.z + w4.w*hB.w;
                }
                pp[0][u2][q2] = qa; pp[1][u2][q2] = qb;
            }
        }
        // fc dot (once per 168 ticks), reads stable h1
        if (ydtick && t < 200) {
            atomicAdd(&yacc[ub], sfcw[uj] * shs[(2 + ub) * SHP + uj]);
        }
        __syncthreads();

        // ================= Phase B: cell updates =================
        if (t < 200) {
            if (tick < 8064) {               // L0, global step g0 = tick
                const int s = tick / LSEQ, p = tick % LSEQ;
                float x;
                if (s == 0)            x = xrow[p];
                else if (p < LSEQ - 1) x = xrow[p + 1];
                else                   x = ybuf[ub];
                const int j = uj, b = ub;
                const int ro = 300 + j;
                float Gi = sb0[j]       + sw0[j]       * x + g0s[b][j];
                float Gf = sb0[100 + j] + sw0[100 + j] * x + g0s[b][100 + j];
                float Gg = sb0[200 + j] + sw0[200 + j] * x + g0s[b][200 + j];
                float po = (ro < 384) ? g0s[b][ro]
                                      : (pp[b][ro-384][0] + pp[b][ro-384][1] +
                                         pp[b][ro-384][2] + pp[b][ro-384][3]);
                float Go = sb0[ro] + sw0[ro] * x + po;
                c0 = sigmoidf_(Gf) * c0 + sigmoidf_(Gi) * tanhf_(Gg);
                shs[b * SHP + j] = sigmoidf_(Go) * tanhf_(c0);
            }
        } else if (t < 400) {
            if (tick >= 1 && tick <= 8064) { // L1, global step g1 = tick-1
                const int j = uj, b = ub;
                const int rg = 200 + j, ro = 300 + j;
                float Gi = sb1[j]       + g1a[b][j]       + g1b[b][j];
                float Gf = sb1[100 + j] + g1a[b][100 + j] + g1b[b][100 + j];
                float bg = (rg < 256) ? g1b[b][rg]
                                      : (pp[b][rg-224][0] + pp[b][rg-224][1] +
                                         pp[b][rg-224][2] + pp[b][rg-224][3]);
                float Gg = sb1[rg] + g1a[b][rg] + bg;
                float Ao = (ro < 384) ? g1a[b][ro]
                                      : (pp[b][ro-368][0] + pp[b][ro-368][1] +
                                         pp[b][ro-368][2] + pp[b][ro-368][3]);
                float Bo = pp[b][ro-224][0] + pp[b][ro-224][1] +
                           pp[b][ro-224][2] + pp[b][ro-224][3];
                float Go = sb1[ro] + Ao + Bo;
                c1 = sigmoidf_(Gf) * c1 + sigmoidf_(Gi) * tanhf_(Gg);
                shs[(2 + b) * SHP + j] = sigmoidf_(Go) * tanhf_(c1);
            }
        } else if (t == 480) {
            if (ydtick) {
                const int s = (tick - 2) / LSEQ;
                float y0 = yacc[0] + fcb0;
                float y1 = yacc[1] + fcb0;
                ybuf[0] = y0; ybuf[1] = y1;
                out[b0 * STEPS + s]       = y0;
                out[(b0 + 1) * STEPS + s] = y1;
                yacc[0] = 0.0f; yacc[1] = 0.0f;
            }
        }
        __syncthreads();
    }
}

extern "C" void kernel_launch(void* const* d_in, const int* in_sizes, int n_in,
                              void* d_out, int out_size, void* d_ws, size_t ws_size,
                              hipStream_t stream) {
    const float* X    = (const float*)d_in[0];
    const float* Wih0 = (const float*)d_in[1];
    const float* Whh0 = (const float*)d_in[2];
    const float* bih0 = (const float*)d_in[3];
    const float* bhh0 = (const float*)d_in[4];
    const float* Wih1 = (const float*)d_in[5];
    const float* Whh1 = (const float*)d_in[6];
    const float* bih1 = (const float*)d_in[7];
    const float* bhh1 = (const float*)d_in[8];
    const float* fcw  = (const float*)d_in[9];
    const float* fcb  = (const float*)d_in[10];
    float* out = (float*)d_out;
    float* wsT = (float*)d_ws;   // 112*176 floats = 78,848 B

    hipLaunchKernelGGL(prep_kernel, dim3((SHP * NPOOL + 255) / 256), dim3(256), 0, stream,
                       Whh0, Wih1, Whh1, wsT);
    hipLaunchKernelGGL(lstm_kernel, dim3(256), dim3(512), 0, stream,
                       X, Wih0, Whh0, bih0, bhh0, Wih1, Whh1, bih1, bhh1,
                       fcw, fcb, wsT, out);
}

// Round 5
// 136732.849 us; speedup vs baseline: 2.0576x; 2.0576x over previous
//
#include <hip/hip_runtime.h>

#define HH    100
#define G4    400
#define LSEQ  168
#define STEPS 48
#define NTICK 8066     // L0 at tick t (t<8064), L1 at tick t-1
#define SHP   112      // padded h stride (zeros beyond 100)
#define SK    28       // k per slice (4 slices x 28 = 112)
#define PSTR  9        // partial row stride (9 coprime 32 banks)

// LDS float offsets
#define OFF_WLDS 0              // [288][100]  Wih1 rows 112..399  (units 512..799)
#define OFF_PART 28800          // [1200][9]   per-(row,slice,batch) partials
#define OFF_H0   39600          // [2][112]    h layer0, per batch
#define OFF_H1   39824          // [2][112]    h layer1
#define OFF_YY   40048          // yacc[2], ybuf[2]
#define LDS_FLOATS 40052
#define LDS_BYTES  (LDS_FLOATS * 4)   // 160,208 B <= 163,840

__device__ __forceinline__ float sigmoidf_(float x) {
    return 1.0f / (1.0f + __expf(-x));
}
__device__ __forceinline__ float tanhf_(float x) {
    return 1.0f - 2.0f / (__expf(2.0f * x) + 1.0f);
}

#define DOT4(acc, w4, h4) acc += (w4).x*(h4).x + (w4).y*(h4).y + (w4).z*(h4).z + (w4).w*(h4).w

// Unit map (1200 row-units, unit u -> one gate row's dot-product):
//   u <  400 : Whh0 row u        (input h0) -> L0 gates
//   u <  800 : Wih1 row u-400    (input h0) -> L1 "a" part
//   u < 1200 : Whh1 row u-800    (input h1) -> L1 "b" part
// Storage: units 0..511 regs (2 frags/thread), 512..799 LDS, 800..1199 L2 stream.
// Thread (s = t&3, v = t>>2): slice s of rows {2v, 2v+1}, {512+v}, {768+v if v<32},
// {800+v}, {1056+v if v<144}.
__global__
__attribute__((amdgpu_flat_work_group_size(1024, 1024)))
void lstm_kernel(const float* __restrict__ X,     // (512,168)
                 const float* __restrict__ Wih0,  // (400,1)
                 const float* __restrict__ Whh0,  // (400,100)
                 const float* __restrict__ bih0,
                 const float* __restrict__ bhh0,
                 const float* __restrict__ Wih1,  // (400,100)
                 const float* __restrict__ Whh1,  // (400,100)
                 const float* __restrict__ bih1,
                 const float* __restrict__ bhh1,
                 const float* __restrict__ fcw,   // (100)
                 const float* __restrict__ fcb,   // (1)
                 float* __restrict__ out)         // (512,48)
{
    extern __shared__ float lds[];
    float* const P   = &lds[OFF_PART];
    float* const h0s = &lds[OFF_H0];
    float* const h1s = &lds[OFF_H1];
    float* const yy  = &lds[OFF_YY];

    const int t  = threadIdx.x;
    const int s  = t & 3;
    const int v  = t >> 2;
    const int b0 = blockIdx.x * 2;
    const int kb = s * SK;

    // ---- one-time init ----
    for (int i = t; i < 4 * SHP; i += 1024) h0s[i] = 0.0f;   // covers h0s+h1s
    if (t < 4) yy[t] = 0.0f;
    for (int idx = t; idx < 288 * HH; idx += 1024) {
        int r = idx / HH, k = idx % HH;
        lds[OFF_WLDS + idx] = Wih1[(112 + r) * HH + k];
    }
    const float fcb0 = fcb[0];

    // ---- register weights: slice s of rows 2v, 2v+1 (56 floats total) ----
    float4 wr0[7], wr1[7];
    {
        const int r0 = 2 * v, r1 = 2 * v + 1;
        const float* W0 = (r0 < 400) ? (Whh0 + r0 * HH) : (Wih1 + (r0 - 400) * HH);
        const float* W1 = (r1 < 400) ? (Whh0 + r1 * HH) : (Wih1 + (r1 - 400) * HH);
        #pragma unroll
        for (int i = 0; i < 7; ++i) {
            if (s < 3 || i < 4) {
                wr0[i] = *(const float4*)(W0 + kb + 4 * i);
                wr1[i] = *(const float4*)(W1 + kb + 4 * i);
            } else {
                wr0[i] = make_float4(0.f, 0.f, 0.f, 0.f);
                wr1[i] = make_float4(0.f, 0.f, 0.f, 0.f);
            }
        }
    }

    // ---- Phase-B per-thread constants (registers, not LDS) ----
    int ub = 0, uj = 0;
    float pbb[4] = {0.f, 0.f, 0.f, 0.f}, pwx[4] = {0.f, 0.f, 0.f, 0.f};
    float fcwr = 0.0f;
    if (t < 200) {
        ub = t / 100; uj = t % 100;
        #pragma unroll
        for (int g = 0; g < 4; ++g) {
            pbb[g] = bih0[g * 100 + uj] + bhh0[g * 100 + uj];
            pwx[g] = Wih0[g * 100 + uj];
        }
        fcwr = fcw[uj];
    } else if (t < 400) {
        ub = (t - 200) / 100; uj = (t - 200) % 100;
        #pragma unroll
        for (int g = 0; g < 4; ++g)
            pbb[g] = bih1[g * 100 + uj] + bhh1[g * 100 + uj];
    }
    const float* xrow = X + (b0 + ub) * LSEQ;

    float c0 = 0.0f, c1 = 0.0f;
    const float* wsA = Whh1 + v * HH + kb;            // stream row A: unit 800+v
    const float* wsB = Whh1 + (256 + v) * HH + kb;    // stream row B: unit 1056+v (v<144)
    const float* wlA = &lds[OFF_WLDS + v * HH + kb];         // LDS row: unit 512+v
    const float* wlB = &lds[OFF_WLDS + (256 + v) * HH + kb]; // extra LDS row: unit 768+v (v<32)

    __syncthreads();

    #pragma unroll 1
    for (int tick = 0; tick < NTICK; ++tick) {
        const bool ydtick = (tick >= 2) && ((tick - 2) % LSEQ == (LSEQ - 1));

        // ============ Phase A ============
        // Kick off stream-A weight loads first (vmem overlaps VALU below).
        float4 w4A[7];
        #pragma unroll
        for (int i = 0; i < 7; ++i)
            if (s < 3 || i < 4) w4A[i] = *(const float4*)(wsA + 4 * i);

        // pass 1: reg rows 2v,2v+1 + LDS row 512+v (all h0 input)
        {
            float a0A = 0.f, a0B = 0.f, a1A = 0.f, a1B = 0.f, aLA = 0.f, aLB = 0.f;
            #pragma unroll
            for (int i = 0; i < 7; ++i) {
                if (s < 3 || i < 4) {
                    const float4 hA = *(const float4*)(h0s + kb + 4 * i);
                    const float4 hB = *(const float4*)(h0s + SHP + kb + 4 * i);
                    const float4 wL = *(const float4*)(wlA + 4 * i);
                    DOT4(a0A, wr0[i], hA); DOT4(a0B, wr0[i], hB);
                    DOT4(a1A, wr1[i], hA); DOT4(a1B, wr1[i], hB);
                    DOT4(aLA, wL, hA);     DOT4(aLB, wL, hB);
                }
            }
            P[(2 * v) * PSTR + 2 * s]         = a0A;
            P[(2 * v) * PSTR + 2 * s + 1]     = a0B;
            P[(2 * v + 1) * PSTR + 2 * s]     = a1A;
            P[(2 * v + 1) * PSTR + 2 * s + 1] = a1B;
            P[(512 + v) * PSTR + 2 * s]       = aLA;
            P[(512 + v) * PSTR + 2 * s + 1]   = aLB;
        }
        // extra LDS row for v<32 (unit 768+v, h0 input)
        if (v < 32) {
            float aA = 0.f, aB = 0.f;
            #pragma unroll
            for (int i = 0; i < 7; ++i) {
                if (s < 3 || i < 4) {
                    const float4 hA = *(const float4*)(h0s + kb + 4 * i);
                    const float4 hB = *(const float4*)(h0s + SHP + kb + 4 * i);
                    const float4 wL = *(const float4*)(wlB + 4 * i);
                    DOT4(aA, wL, hA); DOT4(aB, wL, hB);
                }
            }
            P[(768 + v) * PSTR + 2 * s]     = aA;
            P[(768 + v) * PSTR + 2 * s + 1] = aB;
        }
        // stream row A (unit 800+v, h1 input)
        {
            float aA = 0.f, aB = 0.f;
            #pragma unroll
            for (int i = 0; i < 7; ++i) {
                if (s < 3 || i < 4) {
                    const float4 hA = *(const float4*)(h1s + kb + 4 * i);
                    const float4 hB = *(const float4*)(h1s + SHP + kb + 4 * i);
                    DOT4(aA, w4A[i], hA); DOT4(aB, w4A[i], hB);
                }
            }
            P[(800 + v) * PSTR + 2 * s]     = aA;
            P[(800 + v) * PSTR + 2 * s + 1] = aB;
        }
        // stream row B (unit 1056+v, h1 input), v<144
        if (v < 144) {
            float aA = 0.f, aB = 0.f;
            #pragma unroll
            for (int i = 0; i < 7; ++i) {
                if (s < 3 || i < 4) {
                    const float4 w4 = *(const float4*)(wsB + 4 * i);
                    const float4 hA = *(const float4*)(h1s + kb + 4 * i);
                    const float4 hB = *(const float4*)(h1s + SHP + kb + 4 * i);
                    DOT4(aA, w4, hA); DOT4(aB, w4, hB);
                }
            }
            P[(1056 + v) * PSTR + 2 * s]     = aA;
            P[(1056 + v) * PSTR + 2 * s + 1] = aB;
        }
        // fc dot (once per 168 ticks), reads stable h1
        if (ydtick && t < 200) {
            atomicAdd(&yy[ub], fcwr * h1s[ub * SHP + uj]);
        }
        __syncthreads();

        // ============ Phase B ============
        if (t < 200) {
            if (tick < 8064) {               // L0, global step g0 = tick
                const int st = tick / LSEQ, p = tick % LSEQ;
                float x;
                if (st == 0)           x = xrow[p];
                else if (p < LSEQ - 1) x = xrow[p + 1];
                else                   x = yy[2 + ub];
                float G[4];
                #pragma unroll
                for (int g = 0; g < 4; ++g) {
                    const float* pr = &P[(g * 100 + uj) * PSTR + ub];
                    G[g] = pbb[g] + pwx[g] * x + pr[0] + pr[2] + pr[4] + pr[6];
                }
                c0 = sigmoidf_(G[1]) * c0 + sigmoidf_(G[0]) * tanhf_(G[2]);
                h0s[ub * SHP + uj] = sigmoidf_(G[3]) * tanhf_(c0);
            }
        } else if (t < 400) {
            if (tick >= 1 && tick <= 8064) { // L1, global step g1 = tick-1
                float G[4];
                #pragma unroll
                for (int g = 0; g < 4; ++g) {
                    const float* pa = &P[(400 + g * 100 + uj) * PSTR + ub];
                    const float* pb = &P[(800 + g * 100 + uj) * PSTR + ub];
                    G[g] = pbb[g] + pa[0] + pa[2] + pa[4] + pa[6]
                                  + pb[0] + pb[2] + pb[4] + pb[6];
                }
                c1 = sigmoidf_(G[1]) * c1 + sigmoidf_(G[0]) * tanhf_(G[2]);
                h1s[ub * SHP + uj] = sigmoidf_(G[3]) * tanhf_(c1);
            }
        } else if (t == 1023) {
            if (ydtick) {
                const int st = (tick - 2) / LSEQ;
                float y0 = yy[0] + fcb0;
                float y1 = yy[1] + fcb0;
                yy[2] = y0; yy[3] = y1;
                out[b0 * STEPS + st]       = y0;
                out[(b0 + 1) * STEPS + st] = y1;
                yy[0] = 0.0f; yy[1] = 0.0f;
            }
        }
        __syncthreads();
    }
}

extern "C" void kernel_launch(void* const* d_in, const int* in_sizes, int n_in,
                              void* d_out, int out_size, void* d_ws, size_t ws_size,
                              hipStream_t stream) {
    const float* X    = (const float*)d_in[0];
    const float* Wih0 = (const float*)d_in[1];
    const float* Whh0 = (const float*)d_in[2];
    const float* bih0 = (const float*)d_in[3];
    const float* bhh0 = (const float*)d_in[4];
    const float* Wih1 = (const float*)d_in[5];
    const float* Whh1 = (const float*)d_in[6];
    const float* bih1 = (const float*)d_in[7];
    const float* bhh1 = (const float*)d_in[8];
    const float* fcw  = (const float*)d_in[9];
    const float* fcb  = (const float*)d_in[10];
    float* out = (float*)d_out;

    // >64 KB dynamic LDS needs the attribute; host-side, idempotent, graph-safe.
    static_assert(LDS_BYTES <= 163840, "LDS over 160 KiB");
    (void)hipFuncSetAttribute((const void*)lstm_kernel,
                              hipFuncAttributeMaxDynamicSharedMemorySize,
                              LDS_BYTES);
    hipLaunchKernelGGL(lstm_kernel, dim3(256), dim3(1024), LDS_BYTES, stream,
                       X, Wih0, Whh0, bih0, bhh0, Wih1, Whh1, bih1, bhh1,
                       fcw, fcb, out);
}